// Round 1
// baseline (425.372 us; speedup 1.0000x reference)
//
#include <hip/hip_runtime.h>

// Apply 4x4 gate U to wires {5,13} of a 26-wire qubit state (2^26 fp32 amps).
// Wire w -> flat-index bit (25-w): wires {5,13} -> bits {20,12}.
// Target digit t = bit20*2 + bit12 (wire 5 is INDEX[0] -> high digit).
// Each thread processes 4 consecutive rest indices (contiguous in memory,
// since rest bits 0..11 sit below both inserted bits) via float4 ld/st.

#define BIT_LO 12u   // wire 13
#define BIT_HI 20u   // wire 5

__global__ __launch_bounds__(256) void unitary_5_13_kernel(
    const float* __restrict__ x,
    const float* __restrict__ U,
    float* __restrict__ out)
{
    const unsigned tid  = blockIdx.x * blockDim.x + threadIdx.x; // 0 .. 2^22-1
    const unsigned rest = tid << 2;                              // 0 .. 2^24-4, multiple of 4

    // Insert zero bits at positions 12 and 20:
    //   rest bits [0..11]  -> flat bits [0..11]
    //   rest bits [12..18] -> flat bits [13..19]   (<<1)
    //   rest bits [19..23] -> flat bits [21..25]   (<<2)
    const unsigned base = (rest & 0x00000FFFu)
                        | ((rest & 0x0007F000u) << 1)
                        | ((rest & 0x00F80000u) << 2);

    const unsigned i0 = base;                            // t=0: bit20=0, bit12=0
    const unsigned i1 = base | (1u << BIT_LO);           // t=1: bit20=0, bit12=1
    const unsigned i2 = base | (1u << BIT_HI);           // t=2: bit20=1, bit12=0
    const unsigned i3 = base | (1u << BIT_HI) | (1u << BIT_LO); // t=3

    const float4 a0 = *(const float4*)(x + i0);
    const float4 a1 = *(const float4*)(x + i1);
    const float4 a2 = *(const float4*)(x + i2);
    const float4 a3 = *(const float4*)(x + i3);

    // U is 4x4 row-major; uniform address -> cached (L1/L2), negligible traffic.
    const float u00 = U[0],  u01 = U[1],  u02 = U[2],  u03 = U[3];
    const float u10 = U[4],  u11 = U[5],  u12 = U[6],  u13 = U[7];
    const float u20 = U[8],  u21 = U[9],  u22 = U[10], u23 = U[11];
    const float u30 = U[12], u31 = U[13], u32 = U[14], u33 = U[15];

    float4 o0, o1, o2, o3;
    o0.x = u00*a0.x + u01*a1.x + u02*a2.x + u03*a3.x;
    o0.y = u00*a0.y + u01*a1.y + u02*a2.y + u03*a3.y;
    o0.z = u00*a0.z + u01*a1.z + u02*a2.z + u03*a3.z;
    o0.w = u00*a0.w + u01*a1.w + u02*a2.w + u03*a3.w;

    o1.x = u10*a0.x + u11*a1.x + u12*a2.x + u13*a3.x;
    o1.y = u10*a0.y + u11*a1.y + u12*a2.y + u13*a3.y;
    o1.z = u10*a0.z + u11*a1.z + u12*a2.z + u13*a3.z;
    o1.w = u10*a0.w + u11*a1.w + u12*a2.w + u13*a3.w;

    o2.x = u20*a0.x + u21*a1.x + u22*a2.x + u23*a3.x;
    o2.y = u20*a0.y + u21*a1.y + u22*a2.y + u23*a3.y;
    o2.z = u20*a0.z + u21*a1.z + u22*a2.z + u23*a3.z;
    o2.w = u20*a0.w + u21*a1.w + u22*a2.w + u23*a3.w;

    o3.x = u30*a0.x + u31*a1.x + u32*a2.x + u33*a3.x;
    o3.y = u30*a0.y + u31*a1.y + u32*a2.y + u33*a3.y;
    o3.z = u30*a0.z + u31*a1.z + u32*a2.z + u33*a3.z;
    o3.w = u30*a0.w + u31*a1.w + u32*a2.w + u33*a3.w;

    *(float4*)(out + i0) = o0;
    *(float4*)(out + i1) = o1;
    *(float4*)(out + i2) = o2;
    *(float4*)(out + i3) = o3;
}

extern "C" void kernel_launch(void* const* d_in, const int* in_sizes, int n_in,
                              void* d_out, int out_size, void* d_ws, size_t ws_size,
                              hipStream_t stream)
{
    const float* x = (const float*)d_in[0];   // 2^26 fp32 state amplitudes
    const float* U = (const float*)d_in[1];   // 4x4 fp32 gate
    float* out = (float*)d_out;               // 2^26 fp32

    // REST = 2^24 rest indices, 4 per thread -> 2^22 threads
    const int block = 256;
    const int grid  = (1 << 22) / block;      // 16384 blocks
    unitary_5_13_kernel<<<grid, block, 0, stream>>>(x, U, out);
}

// Round 2
// 416.707 us; speedup vs baseline: 1.0208x; 1.0208x over previous
//
#include <hip/hip_runtime.h>

// Apply 4x4 gate U to wires {5,13} of a 26-wire qubit state (2^26 fp32 amps).
// Wire w -> flat-index bit (25-w): wires {5,13} -> bits {20,12}.
// Target digit t = bit20*2 + bit12 (wire 5 is INDEX[0] -> high digit).
// Each thread processes 4 consecutive rest indices (contiguous in memory,
// since rest bits 0..11 sit below both inserted bits) via float4 ld/st.
// All global accesses are non-temporal: pure streaming, zero reuse, keep L2 clean.

#define BIT_LO 12u   // wire 13
#define BIT_HI 20u   // wire 5

typedef float v4f __attribute__((ext_vector_type(4)));

__global__ __launch_bounds__(256) void unitary_5_13_kernel(
    const float* __restrict__ x,
    const float* __restrict__ U,
    float* __restrict__ out)
{
    const unsigned tid  = blockIdx.x * blockDim.x + threadIdx.x; // 0 .. 2^22-1
    const unsigned rest = tid << 2;                              // 0 .. 2^24-4, multiple of 4

    // Insert zero bits at positions 12 and 20:
    //   rest bits [0..11]  -> flat bits [0..11]
    //   rest bits [12..18] -> flat bits [13..19]   (<<1)
    //   rest bits [19..23] -> flat bits [21..25]   (<<2)
    const unsigned base = (rest & 0x00000FFFu)
                        | ((rest & 0x0007F000u) << 1)
                        | ((rest & 0x00F80000u) << 2);

    const unsigned i0 = base;                                   // bit20=0, bit12=0
    const unsigned i1 = base | (1u << BIT_LO);                  // bit20=0, bit12=1
    const unsigned i2 = base | (1u << BIT_HI);                  // bit20=1, bit12=0
    const unsigned i3 = base | (1u << BIT_HI) | (1u << BIT_LO); // bit20=1, bit12=1

    const v4f a0 = __builtin_nontemporal_load((const v4f*)(x + i0));
    const v4f a1 = __builtin_nontemporal_load((const v4f*)(x + i1));
    const v4f a2 = __builtin_nontemporal_load((const v4f*)(x + i2));
    const v4f a3 = __builtin_nontemporal_load((const v4f*)(x + i3));

    // U is 4x4 row-major; uniform address -> scalar loads, negligible traffic.
    const float u00 = U[0],  u01 = U[1],  u02 = U[2],  u03 = U[3];
    const float u10 = U[4],  u11 = U[5],  u12 = U[6],  u13 = U[7];
    const float u20 = U[8],  u21 = U[9],  u22 = U[10], u23 = U[11];
    const float u30 = U[12], u31 = U[13], u32 = U[14], u33 = U[15];

    v4f o0, o1, o2, o3;
    o0 = u00*a0 + u01*a1 + u02*a2 + u03*a3;
    o1 = u10*a0 + u11*a1 + u12*a2 + u13*a3;
    o2 = u20*a0 + u21*a1 + u22*a2 + u23*a3;
    o3 = u30*a0 + u31*a1 + u32*a2 + u33*a3;

    __builtin_nontemporal_store(o0, (v4f*)(out + i0));
    __builtin_nontemporal_store(o1, (v4f*)(out + i1));
    __builtin_nontemporal_store(o2, (v4f*)(out + i2));
    __builtin_nontemporal_store(o3, (v4f*)(out + i3));
}

extern "C" void kernel_launch(void* const* d_in, const int* in_sizes, int n_in,
                              void* d_out, int out_size, void* d_ws, size_t ws_size,
                              hipStream_t stream)
{
    const float* x = (const float*)d_in[0];   // 2^26 fp32 state amplitudes
    const float* U = (const float*)d_in[1];   // 4x4 fp32 gate
    float* out = (float*)d_out;               // 2^26 fp32

    // REST = 2^24 rest indices, 4 per thread -> 2^22 threads
    const int block = 256;
    const int grid  = (1 << 22) / block;      // 16384 blocks
    unitary_5_13_kernel<<<grid, block, 0, stream>>>(x, U, out);
}